// Round 1
// baseline (532.921 us; speedup 1.0000x reference)
//
#include <hip/hip_runtime.h>

// Problem constants (from reference): B=256 batch, N=256 generators, D=512 dims.
#define BB 256
#define NN 256
#define DD 512

constexpr float EPSF = 1e-8f;
constexpr size_t PD_OFF = (size_t)BB * DD;                          // new_central elems
constexpr size_t NE_OFF = PD_OFF + (size_t)BB * (NN + DD) * DD;     // + new_pd elems

__device__ __forceinline__ void relax1(float rad_noerr, float e, float c,
                                       float& lam, float& del,
                                       float& ncv, float& nev) {
    float rad = rad_noerr + fabsf(e);
    float lo = c - rad;
    float up = c + rad;
    float rl = fmaxf(lo, 0.f);
    float ru = fmaxf(up, 0.f);
    float l = (ru - rl) / (up - lo + EPSF);
    if (lo >= 0.f) l = 1.f;
    if (up <  0.f) l = 0.f;
    if (l != l)    l = 0.f;            // nan_to_num
    l = fminf(fmaxf(l, 0.f), 1.f);     // clip
    float beta = (rl - l * lo) * 0.5f;
    lam = l;
    del = fabsf(beta);
    ncv = l * c + beta;
    nev = l * e;
}

// One block handles (b, half-of-D = 256 dims). 256 threads:
//   d4 = tid & 63  -> which float4 column group (64 * 4 = 256 dims)
//   nc = tid >> 6  -> which chunk of 64 n-rows (4 chunks * 64 = 256 rows)
// Reads pd once (coalesced 1KB/wave float4 rows), reduces |pd| over N,
// computes lam/delta and writes new_central/new_err + lam/delta to ws.
__global__ __launch_bounds__(256) void stats_kernel(
    const float* __restrict__ cv, const float* __restrict__ pd,
    const float* __restrict__ err, float* __restrict__ out,
    float* __restrict__ lam_ws, float* __restrict__ delta_ws)
{
    const int blk   = blockIdx.x;          // 0..511
    const int b     = blk >> 1;
    const int dbase = (blk & 1) * 256;
    const int tid   = threadIdx.x;
    const int d4    = tid & 63;
    const int nc    = tid >> 6;

    const float4* pdrow = (const float4*)(pd + (size_t)b * NN * DD + dbase);
    float4 acc = make_float4(0.f, 0.f, 0.f, 0.f);
    const int n0 = nc * 64;
#pragma unroll 8
    for (int k = 0; k < 64; ++k) {
        float4 v = pdrow[(size_t)(n0 + k) * (DD / 4) + d4];
        acc.x += fabsf(v.x); acc.y += fabsf(v.y);
        acc.z += fabsf(v.z); acc.w += fabsf(v.w);
    }

    __shared__ float4 part[4][64];
    part[nc][d4] = acc;
    __syncthreads();

    if (nc == 0) {
        float4 a0 = part[0][d4], a1 = part[1][d4], a2 = part[2][d4], a3 = part[3][d4];
        float rads[4] = {a0.x + a1.x + a2.x + a3.x,
                         a0.y + a1.y + a2.y + a3.y,
                         a0.z + a1.z + a2.z + a3.z,
                         a0.w + a1.w + a2.w + a3.w};
        const size_t base = (size_t)b * DD + dbase + d4 * 4;
        float4 ev = *(const float4*)(err + base);
        float4 cb = *(const float4*)(cv + base);
        float e[4] = {ev.x, ev.y, ev.z, ev.w};
        float c[4] = {cb.x, cb.y, cb.z, cb.w};
        float lamv[4], delv[4], ncv[4], nev[4];
#pragma unroll
        for (int j = 0; j < 4; ++j)
            relax1(rads[j], e[j], c[j], lamv[j], delv[j], ncv[j], nev[j]);

        *(float4*)(out + base)           = make_float4(ncv[0], ncv[1], ncv[2], ncv[3]);
        *(float4*)(out + NE_OFF + base)  = make_float4(nev[0], nev[1], nev[2], nev[3]);
        *(float4*)(lam_ws + base)        = make_float4(lamv[0], lamv[1], lamv[2], lamv[3]);
        *(float4*)(delta_ws + base)      = make_float4(delv[0], delv[1], delv[2], delv[3]);
    }
}

// Writes the entire new_pd block (B, N+D, D) as float4s, grid-stride.
// Rows < N: scaled_pd = pd * lam (lam is 0.5 MB -> L2 resident).
// Rows >= N: diag block, zeros except the single diagonal element.
__global__ __launch_bounds__(256) void writepd_kernel(
    const float* __restrict__ pd,
    const float* __restrict__ lam_ws,
    const float* __restrict__ delta_ws,
    float4* __restrict__ outpd)
{
    const size_t total = (size_t)BB * (NN + DD) * (DD / 4);   // 25,165,824 float4
    size_t idx = (size_t)blockIdx.x * blockDim.x + threadIdx.x;
    const size_t stride = (size_t)gridDim.x * blockDim.x;
    for (; idx < total; idx += stride) {
        const unsigned d4     = (unsigned)(idx & (DD / 4 - 1));      // 0..127
        const unsigned row_id = (unsigned)(idx >> 7);                // b*768 + r
        const unsigned b      = row_id / (NN + DD);
        const unsigned r      = row_id - b * (NN + DD);
        float4 o;
        if (r < NN) {
            float4 v = ((const float4*)pd)[((size_t)b * NN + r) * (DD / 4) + d4];
            float4 l = ((const float4*)lam_ws)[(size_t)b * (DD / 4) + d4];
            o = make_float4(v.x * l.x, v.y * l.y, v.z * l.z, v.w * l.w);
        } else {
            const unsigned i = r - NN;                               // 0..511
            o = make_float4(0.f, 0.f, 0.f, 0.f);
            if ((i >> 2) == d4) {
                float dv = delta_ws[(size_t)b * DD + i];
                ((float*)&o)[i & 3] = dv;
            }
        }
        outpd[idx] = o;
    }
}

extern "C" void kernel_launch(void* const* d_in, const int* in_sizes, int n_in,
                              void* d_out, int out_size, void* d_ws, size_t ws_size,
                              hipStream_t stream) {
    const float* cv  = (const float*)d_in[0];
    const float* pd  = (const float*)d_in[1];
    const float* err = (const float*)d_in[2];
    float* out = (float*)d_out;

    float* lam_ws   = (float*)d_ws;                  // B*D floats
    float* delta_ws = lam_ws + (size_t)BB * DD;      // B*D floats (1 MB total)

    stats_kernel<<<dim3(BB * 2), dim3(256), 0, stream>>>(cv, pd, err, out, lam_ws, delta_ws);

    // 25.2M float4 total; 12288 blocks x 256 threads -> 8 iterations/thread.
    writepd_kernel<<<dim3(12288), dim3(256), 0, stream>>>(
        pd, lam_ws, delta_ws, (float4*)(out + PD_OFF));
}

// Round 3
// 492.859 us; speedup vs baseline: 1.0813x; 1.0813x over previous
//
#include <hip/hip_runtime.h>

// Problem constants (from reference): B=256 batch, N=256 generators, D=512 dims.
#define BB 256
#define NN 256
#define DD 512
#define RT (NN + DD)   // 768 rows per batch in new_pd

constexpr float EPSF = 1e-8f;
constexpr size_t PD_OFF = (size_t)BB * DD;                      // new_central elems
constexpr size_t NE_OFF = PD_OFF + (size_t)BB * RT * DD;        // + new_pd elems

// Native 4-float vector: __builtin_nontemporal_* requires a native vector
// type, not HIP's HIP_vector_type<float,4> class.
typedef float vfloat4 __attribute__((ext_vector_type(4)));

__device__ __forceinline__ vfloat4 nt_load4(const vfloat4* p) {
    return __builtin_nontemporal_load(p);
}
__device__ __forceinline__ void nt_store4(vfloat4* p, vfloat4 v) {
    __builtin_nontemporal_store(v, p);
}

// One block = (b, 64-dim slice). 256 threads hold the whole 256x64 pd slice
// in registers (16 float4 each):
//   j  = tid & 15   -> float4 column (4 dims)
//   rb = tid >> 4   -> row offset; thread covers rows rb + 16k, k=0..15
// Wave lanes: a 64-lane wave spans rb in {0..3} x j in {0..15}; lanes ^16/^32
// share j, so shfl_xor(16|32) reduces over rows while preserving the column.
__global__ __launch_bounds__(256) void fused_kernel(
    const float* __restrict__ cv, const float* __restrict__ pd,
    const float* __restrict__ err, float* __restrict__ out)
{
    const int bx    = blockIdx.x;          // 0..2047
    const int b     = bx >> 3;
    const int dbase = (bx & 7) * 64;
    const int tid   = threadIdx.x;
    const int j     = tid & 15;
    const int rb    = tid >> 4;

    // ---- load pd slice into registers, accumulate |pd| per column ----
    const vfloat4* pdb = (const vfloat4*)(pd + (size_t)b * NN * DD + dbase);
    vfloat4 data[16];
    float ax = 0.f, ay = 0.f, az = 0.f, aw = 0.f;
#pragma unroll
    for (int k = 0; k < 16; ++k) {
        const int r = rb + (k << 4);
        vfloat4 v = nt_load4(pdb + (size_t)r * (DD / 4) + j);
        data[k] = v;
        ax += fabsf(v.x); ay += fabsf(v.y); az += fabsf(v.z); aw += fabsf(v.w);
    }
    // reduce over rb within the wave (lanes ^16 and ^32 have the same j)
    ax += __shfl_xor(ax, 16); ay += __shfl_xor(ay, 16);
    az += __shfl_xor(az, 16); aw += __shfl_xor(aw, 16);
    ax += __shfl_xor(ax, 32); ay += __shfl_xor(ay, 32);
    az += __shfl_xor(az, 32); aw += __shfl_xor(aw, 32);

    __shared__ float part[4][64];                 // [wave][dim in slice]
    __shared__ __align__(16) float lam_s[64];
    __shared__ float del_s[64];
    const int wave = tid >> 6;
    const int lane = tid & 63;
    if (lane < 16) {                               // lane == j for these lanes
        part[wave][lane * 4 + 0] = ax;
        part[wave][lane * 4 + 1] = ay;
        part[wave][lane * 4 + 2] = az;
        part[wave][lane * 4 + 3] = aw;
    }
    __syncthreads();

    // ---- per-dim relaxation (64 dims handled by threads 0..63) ----
    if (tid < 64) {
        float rad = part[0][tid] + part[1][tid] + part[2][tid] + part[3][tid];
        const size_t gi = (size_t)b * DD + dbase + tid;
        const float c = cv[gi];
        const float e = err[gi];
        rad += fabsf(e);
        const float lo = c - rad, up = c + rad;
        const float rl = fmaxf(lo, 0.f), ru = fmaxf(up, 0.f);
        float l = (ru - rl) / (up - lo + EPSF);
        if (lo >= 0.f) l = 1.f;
        if (up <  0.f) l = 0.f;
        if (l != l)    l = 0.f;                    // nan_to_num
        l = fminf(fmaxf(l, 0.f), 1.f);             // clip
        const float beta = (rl - l * lo) * 0.5f;
        out[gi]          = l * c + beta;           // new_central
        out[NE_OFF + gi] = l * e;                  // new_err
        lam_s[tid] = l;
        del_s[tid] = fabsf(beta);
    }
    __syncthreads();

    // ---- scaled_pd = pd * lam, straight from registers ----
    const vfloat4 lm = *(const vfloat4*)&lam_s[j * 4];   // broadcast within wave
    vfloat4* outb = (vfloat4*)(out + PD_OFF + (size_t)b * RT * DD + dbase);
#pragma unroll
    for (int k = 0; k < 16; ++k) {
        const int r = rb + (k << 4);
        vfloat4 v = data[k];
        v.x *= lm.x; v.y *= lm.y; v.z *= lm.z; v.w *= lm.w;
        nt_store4(outb + (size_t)r * (DD / 4) + j, v);
    }

    // ---- diag block rows (512 rows x 64 cols per block), mostly zeros ----
    vfloat4* diagb = (vfloat4*)(out + PD_OFF + (size_t)b * RT * DD
                                + (size_t)NN * DD + dbase);
#pragma unroll
    for (int k = 0; k < 32; ++k) {
        const int i  = rb + (k << 4);              // global dim row 0..511
        vfloat4 v = (vfloat4)(0.f, 0.f, 0.f, 0.f);
        const int ii = i - dbase;
        if ((unsigned)ii < 64u && (ii >> 2) == j)
            v[ii & 3] = del_s[ii];
        nt_store4(diagb + (size_t)i * (DD / 4) + j, v);
    }
}

extern "C" void kernel_launch(void* const* d_in, const int* in_sizes, int n_in,
                              void* d_out, int out_size, void* d_ws, size_t ws_size,
                              hipStream_t stream) {
    const float* cv  = (const float*)d_in[0];
    const float* pd  = (const float*)d_in[1];
    const float* err = (const float*)d_in[2];
    float* out = (float*)d_out;

    fused_kernel<<<dim3(BB * 8), dim3(256), 0, stream>>>(cv, pd, err, out);
}